// Round 7
// baseline (423.558 us; speedup 1.0000x reference)
//
#include <hip/hip_runtime.h>
#include <hip/hip_bf16.h>

// Problem constants: N=50000, E=800000, G=512, L=3, D=128
#define D_FEAT 128
#define N_GRAPHS 512
#define N_LAYERS 3
#define POOL_DIM (N_LAYERS * D_FEAT)   // 384
#define N_CLASSES 10
#define BN_EPS 1e-5f
#define CAP 64                         // fixed bucket capacity; P(deg>64) ~ 2e-18
#define NBINS 8

typedef __attribute__((ext_vector_type(8))) short bf16x8;
typedef __attribute__((ext_vector_type(8))) unsigned short ushort8;
typedef __attribute__((ext_vector_type(4))) float f32x4;

__device__ __forceinline__ unsigned short f2bf(float f) {
    unsigned u = __builtin_bit_cast(unsigned, f);
    u += 0x7FFFu + ((u >> 16) & 1u);          // round-to-nearest-even
    return (unsigned short)(u >> 16);
}
__device__ __forceinline__ float bf2f(unsigned short h) {
    unsigned u = ((unsigned)h) << 16;
    return __builtin_bit_cast(float, u);
}
__device__ __forceinline__ float bf_lo(unsigned u) {
    return __builtin_bit_cast(float, u << 16);
}
__device__ __forceinline__ float bf_hi(unsigned u) {
    return __builtin_bit_cast(float, u & 0xffff0000u);
}

// ---------------------------------------------------------------------------
// Pass A: radix-partition edges into 8 dst-range sublists of (src,dst) pairs.
// Block-level LDS histogram -> one global reservation per bin -> dense writes.
// ---------------------------------------------------------------------------
__global__ __launch_bounds__(256) void bin_kernel(const int* __restrict__ ei, int E, int N,
                                                  int2* __restrict__ pairs, int binCap,
                                                  int* __restrict__ binCnt) {
    __shared__ int hist[NBINS], base[NBINS], loc[NBINS];
    int per = (E + gridDim.x - 1) / gridDim.x;
    int e0 = blockIdx.x * per;
    int e1 = e0 + per; if (e1 > E) e1 = E;
    int span = (N + NBINS - 1) / NBINS;
    if (threadIdx.x < NBINS) hist[threadIdx.x] = 0;
    __syncthreads();
    for (int e = e0 + threadIdx.x; e < e1; e += 256)
        atomicAdd(&hist[ei[E + e] / span], 1);
    __syncthreads();
    if (threadIdx.x < NBINS) {
        base[threadIdx.x] = atomicAdd(&binCnt[threadIdx.x], hist[threadIdx.x]);
        loc[threadIdx.x] = 0;
    }
    __syncthreads();
    for (int e = e0 + threadIdx.x; e < e1; e += 256) {
        int dst = ei[E + e];
        int src = ei[e];
        int b = dst / span;
        int p = base[b] + atomicAdd(&loc[b], 1);
        pairs[(size_t)b * binCap + p] = make_int2(src, dst);
    }
}

// ---------------------------------------------------------------------------
// Pass B: per-range fill. blockIdx%8 = range = XCD (CP round-robin), so all
// cursor atomics + bucket scatter stay in one XCD's L2; reads only its own
// sublist (1/8 of the edge set).
// ---------------------------------------------------------------------------
__global__ __launch_bounds__(256) void fill_v3(const int2* __restrict__ pairs,
                                               const int* __restrict__ binCnt, int binCap,
                                               int* __restrict__ cursor,
                                               int* __restrict__ bucket) {
    int r = blockIdx.x & 7;
    int chunk = blockIdx.x >> 3;
    int nchunks = gridDim.x >> 3;
    int cnt = binCnt[r];
    int per = (cnt + nchunks - 1) / nchunks;
    int p0 = chunk * per;
    int p1 = p0 + per; if (p1 > cnt) p1 = cnt;
    for (int p = p0 + threadIdx.x; p < p1; p += 256) {
        int2 pr = pairs[(size_t)r * binCap + p];
        int pos = atomicAdd(&cursor[pr.y], 1);
        if (pos < CAP) bucket[(size_t)pr.y * CAP + pos] = pr.x;
    }
}

// Fold BN (eval) + biases into per-column epilogue: out = relu(acc*alpha + beta)
__global__ void prep_kernel(const float* __restrict__ b1, const float* __restrict__ gamma,
                            const float* __restrict__ beta, const float* __restrict__ rm,
                            const float* __restrict__ rv, const float* __restrict__ b2,
                            float* __restrict__ ea, float* __restrict__ eb) {
    int i = blockIdx.x * 256 + threadIdx.x;   // over L*D = 384
    if (i >= N_LAYERS * D_FEAT) return;
    int l = i >> 7, c = i & 127;
    float s = gamma[i] * rsqrtf(rv[i] + BN_EPS);
    ea[(2 * l) * D_FEAT + c] = s;
    eb[(2 * l) * D_FEAT + c] = (b1[i] - rm[i]) * s + beta[i];
    ea[(2 * l + 1) * D_FEAT + c] = 1.0f;
    eb[(2 * l + 1) * D_FEAT + c] = b2[i];
}

__global__ void cvt_x(const float* __restrict__ x, unsigned short* __restrict__ xb, int n4) {
    int i = blockIdx.x * 256 + threadIdx.x;
    if (i < n4) {
        float4 v = ((const float4*)x)[i];
        ushort4 o;
        o.x = f2bf(v.x); o.y = f2bf(v.y); o.z = f2bf(v.z); o.w = f2bf(v.w);
        ((ushort4*)xb)[i] = o;
    }
}

// convert+transpose weights: Wt[slot][n][k] (bf16), slot 2l=W1[l], 2l+1=W2[l]
__global__ void cvt_w(const float* __restrict__ W1, const float* __restrict__ W2,
                      unsigned short* __restrict__ Wt) {
    int idx = blockIdx.x * 256 + threadIdx.x;   // over 2*L*128*128
    if (idx >= 2 * N_LAYERS * D_FEAT * D_FEAT) return;
    int slot = idx >> 14;
    int r = (idx >> 7) & 127;   // n
    int c = idx & 127;          // k
    int l = slot >> 1;
    const float* W = (slot & 1) ? W2 : W1;
    Wt[idx] = f2bf(W[(size_t)l * D_FEAT * D_FEAT + (size_t)c * D_FEAT + r]);
}

// ---------------------------------------------------------------------------
// Fully fused layer: agg (gather into LDS) + GEMM1 + GEMM2 + pooled epilogue.
// NOTE: hprev and outh MUST be distinct buffers (ping-pong) — the gather
// reads arbitrary rows of hprev while other blocks write outh (r6 bug).
// ---------------------------------------------------------------------------
__global__ __launch_bounds__(256) void layer_fused(const unsigned short* __restrict__ hprev,
                                                   const int* __restrict__ deg,
                                                   const int* __restrict__ bucket,
                                                   const unsigned short* __restrict__ Wt1,
                                                   const unsigned short* __restrict__ Wt2,
                                                   const float* __restrict__ ea1,
                                                   const float* __restrict__ eb1,
                                                   const float* __restrict__ ea2,
                                                   const float* __restrict__ eb2,
                                                   const int* __restrict__ batch,
                                                   float* __restrict__ pooled, int loff,
                                                   unsigned short* __restrict__ outh, int n) {
    __shared__ unsigned short As[64][136];
    __shared__ unsigned short Ws[128][136];
    __shared__ int bgsh[64];
    int tid = threadIdx.x;
    int row0 = blockIdx.x * 64;
    int wave = tid >> 6, lane = tid & 63;
    int m0 = wave * 16;
    int lrow = lane & 15, lq = lane >> 4;
    int grp = lane >> 4, sub = lane & 15;
    const uint4* hp = (const uint4*)hprev;

    // stage Wt1 (loads issue early, overlap with gather below)
    #pragma unroll
    for (int i = 0; i < 8; ++i) {
        int idx = tid + i * 256;
        int r = idx >> 4, c = (idx & 15) * 8;
        *(ushort8*)&Ws[r][c] = *(const ushort8*)&Wt1[(size_t)r * D_FEAT + c];
    }
    if (tid < 64)
        bgsh[tid] = (row0 + tid < n) ? batch[row0 + tid] : -1;

    // ---- gather phase: wave handles rows m0..m0+15 as 8 node-pairs ----
    int nbase = row0 + m0;
    for (int pass = 0; pass < 8; ++pass) {
        int n0 = nbase + pass * 2;
        int n1 = n0 + 1;
        bool v0 = (n0 < n), v1 = (n1 < n);
        int d0 = v0 ? deg[n0] : 0; if (d0 > CAP) d0 = CAP;
        int d1 = v1 ? deg[n1] : 0; if (d1 > CAP) d1 = CAP;
        int idx0 = v0 ? bucket[(size_t)n0 * CAP + lane] : 0;
        int idx1 = v1 ? bucket[(size_t)n1 * CAP + lane] : 0;
        int safe = v0 ? n0 : 0;

        float a0[8] = {0.f,0.f,0.f,0.f,0.f,0.f,0.f,0.f};
        float a1[8] = {0.f,0.f,0.f,0.f,0.f,0.f,0.f,0.f};
        int dmax = d0 > d1 ? d0 : d1;

        for (int t = 0; t < dmax; t += 16) {
            bool p0[4], p1[4];
            int r0[4], r1[4];
            #pragma unroll
            for (int q = 0; q < 4; ++q) {
                int e = t + q * 4 + grp;
                int s0 = __shfl(idx0, e & 63);
                int s1 = __shfl(idx1, e & 63);
                p0[q] = e < d0;
                p1[q] = e < d1;
                r0[q] = p0[q] ? s0 : safe;
                r1[q] = p1[q] ? s1 : safe;
            }
            uint4 w0[4], w1[4];
            #pragma unroll
            for (int q = 0; q < 4; ++q) {
                w0[q] = hp[(size_t)r0[q] * 16 + sub];
                w1[q] = hp[(size_t)r1[q] * 16 + sub];
            }
            #pragma unroll
            for (int q = 0; q < 4; ++q) {
                if (p0[q]) {
                    uint4 v = w0[q];
                    a0[0] += bf_lo(v.x); a0[1] += bf_hi(v.x);
                    a0[2] += bf_lo(v.y); a0[3] += bf_hi(v.y);
                    a0[4] += bf_lo(v.z); a0[5] += bf_hi(v.z);
                    a0[6] += bf_lo(v.w); a0[7] += bf_hi(v.w);
                }
                if (p1[q]) {
                    uint4 v = w1[q];
                    a1[0] += bf_lo(v.x); a1[1] += bf_hi(v.x);
                    a1[2] += bf_lo(v.y); a1[3] += bf_hi(v.y);
                    a1[4] += bf_lo(v.z); a1[5] += bf_hi(v.z);
                    a1[6] += bf_lo(v.w); a1[7] += bf_hi(v.w);
                }
            }
        }

        #pragma unroll
        for (int j = 0; j < 8; ++j) {
            a0[j] += __shfl_xor(a0[j], 16);
            a0[j] += __shfl_xor(a0[j], 32);
            a1[j] += __shfl_xor(a1[j], 16);
            a1[j] += __shfl_xor(a1[j], 32);
        }

        // self term (eps=0)
        if (v0) {
            uint4 sv = hp[(size_t)n0 * 16 + sub];
            a0[0] += bf_lo(sv.x); a0[1] += bf_hi(sv.x);
            a0[2] += bf_lo(sv.y); a0[3] += bf_hi(sv.y);
            a0[4] += bf_lo(sv.z); a0[5] += bf_hi(sv.z);
            a0[6] += bf_lo(sv.w); a0[7] += bf_hi(sv.w);
        }
        if (v1) {
            uint4 sv = hp[(size_t)n1 * 16 + sub];
            a1[0] += bf_lo(sv.x); a1[1] += bf_hi(sv.x);
            a1[2] += bf_lo(sv.y); a1[3] += bf_hi(sv.y);
            a1[4] += bf_lo(sv.z); a1[5] += bf_hi(sv.z);
            a1[6] += bf_lo(sv.w); a1[7] += bf_hi(sv.w);
        }

        if (grp == 0) {         // zero rows for invalid nodes too
            int lr = m0 + pass * 2;
            uint4 o;
            o.x = (unsigned)f2bf(a0[0]) | ((unsigned)f2bf(a0[1]) << 16);
            o.y = (unsigned)f2bf(a0[2]) | ((unsigned)f2bf(a0[3]) << 16);
            o.z = (unsigned)f2bf(a0[4]) | ((unsigned)f2bf(a0[5]) << 16);
            o.w = (unsigned)f2bf(a0[6]) | ((unsigned)f2bf(a0[7]) << 16);
            *(uint4*)&As[lr][sub * 8] = o;
            uint4 p;
            p.x = (unsigned)f2bf(a1[0]) | ((unsigned)f2bf(a1[1]) << 16);
            p.y = (unsigned)f2bf(a1[2]) | ((unsigned)f2bf(a1[3]) << 16);
            p.z = (unsigned)f2bf(a1[4]) | ((unsigned)f2bf(a1[5]) << 16);
            p.w = (unsigned)f2bf(a1[6]) | ((unsigned)f2bf(a1[7]) << 16);
            *(uint4*)&As[lr + 1][sub * 8] = p;
        }
    }
    __syncthreads();

    // ---- GEMM 1 ----
    f32x4 acc[8] = {};
    #pragma unroll
    for (int t = 0; t < 4; ++t) {
        bf16x8 a = *(const bf16x8*)&As[m0 + lrow][t * 32 + lq * 8];
        #pragma unroll
        for (int nt = 0; nt < 8; ++nt) {
            bf16x8 b = *(const bf16x8*)&Ws[nt * 16 + lrow][t * 32 + lq * 8];
            acc[nt] = __builtin_amdgcn_mfma_f32_16x16x32_bf16(a, b, acc[nt], 0, 0, 0);
        }
    }
    __syncthreads();

    // epilogue 1 -> z (bf16) into As; stage Wt2 into Ws
    #pragma unroll
    for (int nt = 0; nt < 8; ++nt) {
        int col = nt * 16 + lrow;
        float al = ea1[col], be = eb1[col];
        #pragma unroll
        for (int r = 0; r < 4; ++r) {
            float v = fmaxf(fmaf(acc[nt][r], al, be), 0.f);
            As[m0 + lq * 4 + r][col] = f2bf(v);
        }
    }
    #pragma unroll
    for (int i = 0; i < 8; ++i) {
        int idx = tid + i * 256;
        int r = idx >> 4, c = (idx & 15) * 8;
        *(ushort8*)&Ws[r][c] = *(const ushort8*)&Wt2[(size_t)r * D_FEAT + c];
    }
    __syncthreads();

    // ---- GEMM 2 ----
    f32x4 acc2[8] = {};
    #pragma unroll
    for (int t = 0; t < 4; ++t) {
        bf16x8 a = *(const bf16x8*)&As[m0 + lrow][t * 32 + lq * 8];
        #pragma unroll
        for (int nt = 0; nt < 8; ++nt) {
            bf16x8 b = *(const bf16x8*)&Ws[nt * 16 + lrow][t * 32 + lq * 8];
            acc2[nt] = __builtin_amdgcn_mfma_f32_16x16x32_bf16(a, b, acc2[nt], 0, 0, 0);
        }
    }

    // epilogue 2 -> global h
    #pragma unroll
    for (int nt = 0; nt < 8; ++nt) {
        int col = nt * 16 + lrow;
        float al = ea2[col], be = eb2[col];
        #pragma unroll
        for (int r = 0; r < 4; ++r) {
            int grow = row0 + m0 + lq * 4 + r;
            if (grow < n) {
                float v = fmaxf(fmaf(acc2[nt][r], al, be), 0.f);
                outh[(size_t)grow * D_FEAT + col] = f2bf(v);
            }
        }
    }

    // ---- fused pooling ----
    __syncthreads();                       // all GEMM2 reads of Ws done
    float* Wsf = (float*)Ws;               // 64 x (stride 132) floats
    #pragma unroll
    for (int nt = 0; nt < 8; ++nt) {
        int col = nt * 16 + lrow;
        float al = ea2[col], be = eb2[col];
        #pragma unroll
        for (int r = 0; r < 4; ++r) {
            int lr = m0 + lq * 4 + r;
            float v = fmaxf(fmaf(acc2[nt][r], al, be), 0.f);
            Wsf[lr * 132 + col] = bf2f(f2bf(v));   // match bf16-rounded h
        }
    }
    __syncthreads();

    int c = tid & 127, half = tid >> 7;    // 2 halves x 32 rows each
    int rbeg = half * 32, rend = rbeg + 32;
    int cur = -1; float sum = 0.f;
    for (int r = rbeg; r < rend; ++r) {
        int g = bgsh[r];                   // uniform across the 128 col-threads
        if (g != cur) {
            if (cur >= 0) atomicAdd(&pooled[(size_t)cur * POOL_DIM + loff + c], sum);
            cur = g; sum = 0.f;
        }
        if (g >= 0) sum += Wsf[r * 132 + c];
    }
    if (cur >= 0) atomicAdd(&pooled[(size_t)cur * POOL_DIM + loff + c], sum);
}

// ---------------------------------------------------------------------------
// MLP head (fp32)
// ---------------------------------------------------------------------------
__global__ void fc1_kernel(const float* __restrict__ pooled, const float* __restrict__ W,
                           const float* __restrict__ b, float* __restrict__ out) {
    int idx = blockIdx.x * 256 + threadIdx.x;    // 512*384
    if (idx >= N_GRAPHS * POOL_DIM) return;
    int r = idx / POOL_DIM, c = idx % POOL_DIM;
    float s = b[c];
    const float* prow = pooled + (size_t)r * POOL_DIM;
    for (int k = 0; k < POOL_DIM; ++k)
        s = fmaf(prow[k], W[(size_t)k * POOL_DIM + c], s);
    out[idx] = fmaxf(s, 0.f);
}

__global__ void fc2_kernel(const float* __restrict__ fc1o, const float* __restrict__ W,
                           const float* __restrict__ b, float* __restrict__ out) {
    int idx = blockIdx.x * 256 + threadIdx.x;    // 512*10
    if (idx >= N_GRAPHS * N_CLASSES) return;
    int r = idx / N_CLASSES, c = idx % N_CLASSES;
    float s = b[c];
    const float* prow = fc1o + (size_t)r * POOL_DIM;
    for (int k = 0; k < POOL_DIM; ++k)
        s = fmaf(prow[k], W[(size_t)k * N_CLASSES + c], s);
    out[idx] = s;
}

// ---------------------------------------------------------------------------
extern "C" void kernel_launch(void* const* d_in, const int* in_sizes, int n_in,
                              void* d_out, int out_size, void* d_ws, size_t ws_size,
                              hipStream_t stream) {
    const float* x      = (const float*)d_in[0];
    const int*   ei     = (const int*)  d_in[1];
    const int*   batch  = (const int*)  d_in[2];
    const float* W1     = (const float*)d_in[3];
    const float* b1     = (const float*)d_in[4];
    const float* gamma  = (const float*)d_in[5];
    const float* beta   = (const float*)d_in[6];
    const float* rm     = (const float*)d_in[7];
    const float* rv     = (const float*)d_in[8];
    const float* W2     = (const float*)d_in[9];
    const float* b2     = (const float*)d_in[10];
    const float* lin1W  = (const float*)d_in[11];
    const float* lin1b  = (const float*)d_in[12];
    const float* lin2W  = (const float*)d_in[13];
    const float* lin2b  = (const float*)d_in[14];
    float* out = (float*)d_out;

    const int N = in_sizes[0] / D_FEAT;   // 50000
    const int E = in_sizes[1] / 2;        // 800000
    const int binCap = E / NBINS + 8192;  // bins ~Binomial(E,1/8), 27-sigma slack

    char* ws = (char*)d_ws;
    auto carve = [&](size_t bytes) {
        char* p = ws;
        ws += (bytes + 255) & ~(size_t)255;
        return p;
    };
    int*   cursor    = (int*)  carve((size_t)N * 4);
    int*   binCnt    = (int*)  carve((size_t)NBINS * 4);
    int*   bucket    = (int*)  carve((size_t)N * CAP * 4);
    int2*  pairs     = (int2*) carve((size_t)NBINS * binCap * 8);
    float* ea        = (float*)carve((size_t)2 * N_LAYERS * D_FEAT * 4);
    float* eb        = (float*)carve((size_t)2 * N_LAYERS * D_FEAT * 4);
    unsigned short* Wt   = (unsigned short*)carve((size_t)2 * N_LAYERS * D_FEAT * D_FEAT * 2);
    unsigned short* xb   = (unsigned short*)carve((size_t)N * D_FEAT * 2);
    unsigned short* hb0  = (unsigned short*)carve((size_t)N * D_FEAT * 2);
    unsigned short* hb1  = (unsigned short*)carve((size_t)N * D_FEAT * 2);
    float* pooled    = (float*)carve((size_t)N_GRAPHS * POOL_DIM * 4);
    float* fc1o      = (float*)carve((size_t)N_GRAPHS * POOL_DIM * 4);

    hipMemsetAsync(cursor, 0, (size_t)N * 4, stream);
    hipMemsetAsync(binCnt, 0, (size_t)NBINS * 4, stream);
    hipMemsetAsync(pooled, 0, (size_t)N_GRAPHS * POOL_DIM * 4, stream);
    bin_kernel<<<256, 256, 0, stream>>>(ei, E, N, pairs, binCap, binCnt);
    fill_v3<<<8 * 64, 256, 0, stream>>>(pairs, binCnt, binCap, cursor, bucket);
    prep_kernel<<<2, 256, 0, stream>>>(b1, gamma, beta, rm, rv, b2, ea, eb);
    cvt_x<<<(N * D_FEAT / 4 + 255) / 256, 256, 0, stream>>>(x, xb, N * D_FEAT / 4);
    cvt_w<<<(2 * N_LAYERS * D_FEAT * D_FEAT + 255) / 256, 256, 0, stream>>>(W1, W2, Wt);

    // ping-pong: layer reads hprev, writes the OTHER buffer (gather reads
    // arbitrary rows -> in-place is a race; this was the r6 bug)
    const unsigned short* hprev = xb;
    unsigned short* hbufs[2] = { hb0, hb1 };
    for (int l = 0; l < N_LAYERS; ++l) {
        unsigned short* outh = hbufs[l & 1];
        layer_fused<<<(N + 63) / 64, 256, 0, stream>>>(hprev, cursor, bucket,
                      Wt + (size_t)(2 * l) * D_FEAT * D_FEAT,
                      Wt + (size_t)(2 * l + 1) * D_FEAT * D_FEAT,
                      ea + (size_t)(2 * l) * D_FEAT,
                      eb + (size_t)(2 * l) * D_FEAT,
                      ea + (size_t)(2 * l + 1) * D_FEAT,
                      eb + (size_t)(2 * l + 1) * D_FEAT,
                      batch, pooled, l * D_FEAT, outh, N);
        hprev = outh;
    }
    fc1_kernel<<<(N_GRAPHS * POOL_DIM + 255) / 256, 256, 0, stream>>>(pooled, lin1W, lin1b, fc1o);
    fc2_kernel<<<(N_GRAPHS * N_CLASSES + 255) / 256, 256, 0, stream>>>(fc1o, lin2W, lin2b, out);
}

// Round 8
// 378.046 us; speedup vs baseline: 1.1204x; 1.1204x over previous
//
#include <hip/hip_runtime.h>
#include <hip/hip_bf16.h>

// Problem constants: N=50000, E=800000, G=512, L=3, D=128
#define D_FEAT 128
#define N_GRAPHS 512
#define N_LAYERS 3
#define POOL_DIM (N_LAYERS * D_FEAT)   // 384
#define N_CLASSES 10
#define BN_EPS 1e-5f
#define CAP 64                         // fixed bucket capacity; P(deg>64) ~ 2e-18
#define NBINS 8

// LESSON (r7): gather is latency-bound and needs max occupancy + tiny
// footprint; GEMM needs 52KB LDS. Fusing them caps the gather at ~6 waves/CU
// (19% occ) and tripled its time. Keep them as separate kernels — the ybuf
// round-trip (~25MB, ~4us) is cheap insurance.

typedef __attribute__((ext_vector_type(8))) short bf16x8;
typedef __attribute__((ext_vector_type(8))) unsigned short ushort8;
typedef __attribute__((ext_vector_type(4))) float f32x4;

__device__ __forceinline__ unsigned short f2bf(float f) {
    unsigned u = __builtin_bit_cast(unsigned, f);
    u += 0x7FFFu + ((u >> 16) & 1u);          // round-to-nearest-even
    return (unsigned short)(u >> 16);
}
__device__ __forceinline__ float bf2f(unsigned short h) {
    unsigned u = ((unsigned)h) << 16;
    return __builtin_bit_cast(float, u);
}
__device__ __forceinline__ float bf_lo(unsigned u) {
    return __builtin_bit_cast(float, u << 16);
}
__device__ __forceinline__ float bf_hi(unsigned u) {
    return __builtin_bit_cast(float, u & 0xffff0000u);
}

// ---------------------------------------------------------------------------
// Pass A: radix-partition edges into 8 dst-range sublists of (src,dst) pairs.
// ---------------------------------------------------------------------------
__global__ __launch_bounds__(256) void bin_kernel(const int* __restrict__ ei, int E, int N,
                                                  int2* __restrict__ pairs, int binCap,
                                                  int* __restrict__ binCnt) {
    __shared__ int hist[NBINS], base[NBINS], loc[NBINS];
    int per = (E + gridDim.x - 1) / gridDim.x;
    int e0 = blockIdx.x * per;
    int e1 = e0 + per; if (e1 > E) e1 = E;
    int span = (N + NBINS - 1) / NBINS;
    if (threadIdx.x < NBINS) hist[threadIdx.x] = 0;
    __syncthreads();
    for (int e = e0 + threadIdx.x; e < e1; e += 256)
        atomicAdd(&hist[ei[E + e] / span], 1);
    __syncthreads();
    if (threadIdx.x < NBINS) {
        base[threadIdx.x] = atomicAdd(&binCnt[threadIdx.x], hist[threadIdx.x]);
        loc[threadIdx.x] = 0;
    }
    __syncthreads();
    for (int e = e0 + threadIdx.x; e < e1; e += 256) {
        int dst = ei[E + e];
        int src = ei[e];
        int b = dst / span;
        int p = base[b] + atomicAdd(&loc[b], 1);
        pairs[(size_t)b * binCap + p] = make_int2(src, dst);
    }
}

// ---------------------------------------------------------------------------
// Pass B: per-range fill. blockIdx%8 = range = XCD (CP round-robin): cursor
// atomics + bucket scatter stay in one XCD's L2; reads only its own sublist.
// ---------------------------------------------------------------------------
__global__ __launch_bounds__(256) void fill_v3(const int2* __restrict__ pairs,
                                               const int* __restrict__ binCnt, int binCap,
                                               int* __restrict__ cursor,
                                               int* __restrict__ bucket) {
    int r = blockIdx.x & 7;
    int chunk = blockIdx.x >> 3;
    int nchunks = gridDim.x >> 3;
    int cnt = binCnt[r];
    int per = (cnt + nchunks - 1) / nchunks;
    int p0 = chunk * per;
    int p1 = p0 + per; if (p1 > cnt) p1 = cnt;
    for (int p = p0 + threadIdx.x; p < p1; p += 256) {
        int2 pr = pairs[(size_t)r * binCap + p];
        int pos = atomicAdd(&cursor[pr.y], 1);
        if (pos < CAP) bucket[(size_t)pr.y * CAP + pos] = pr.x;
    }
}

// Fold BN (eval) + biases into per-column epilogue: out = relu(acc*alpha + beta)
__global__ void prep_kernel(const float* __restrict__ b1, const float* __restrict__ gamma,
                            const float* __restrict__ beta, const float* __restrict__ rm,
                            const float* __restrict__ rv, const float* __restrict__ b2,
                            float* __restrict__ ea, float* __restrict__ eb) {
    int i = blockIdx.x * 256 + threadIdx.x;   // over L*D = 384
    if (i >= N_LAYERS * D_FEAT) return;
    int l = i >> 7, c = i & 127;
    float s = gamma[i] * rsqrtf(rv[i] + BN_EPS);
    ea[(2 * l) * D_FEAT + c] = s;
    eb[(2 * l) * D_FEAT + c] = (b1[i] - rm[i]) * s + beta[i];
    ea[(2 * l + 1) * D_FEAT + c] = 1.0f;
    eb[(2 * l + 1) * D_FEAT + c] = b2[i];
}

__global__ void cvt_x(const float* __restrict__ x, unsigned short* __restrict__ xb, int n4) {
    int i = blockIdx.x * 256 + threadIdx.x;
    if (i < n4) {
        float4 v = ((const float4*)x)[i];
        ushort4 o;
        o.x = f2bf(v.x); o.y = f2bf(v.y); o.z = f2bf(v.z); o.w = f2bf(v.w);
        ((ushort4*)xb)[i] = o;
    }
}

// convert+transpose weights: Wt[slot][n][k] (bf16), slot 2l=W1[l], 2l+1=W2[l]
__global__ void cvt_w(const float* __restrict__ W1, const float* __restrict__ W2,
                      unsigned short* __restrict__ Wt) {
    int idx = blockIdx.x * 256 + threadIdx.x;   // over 2*L*128*128
    if (idx >= 2 * N_LAYERS * D_FEAT * D_FEAT) return;
    int slot = idx >> 14;
    int r = (idx >> 7) & 127;   // n
    int c = idx & 127;          // k
    int l = slot >> 1;
    const float* W = (slot & 1) ? W2 : W1;
    Wt[idx] = f2bf(W[(size_t)l * D_FEAT * D_FEAT + (size_t)c * D_FEAT + r]);
}

// ---------------------------------------------------------------------------
// Aggregation: one wave per TWO nodes, zero LDS, high occupancy. Per 16-edge
// chunk: compute all 8 gather addresses (masked lanes clamp to the valid
// self row), issue 8 UNCONDITIONAL dwordx4 loads back-to-back, predicated
// fp32 accumulate, butterfly combine. 4 lane-groups of 16 = full 256B row.
// ---------------------------------------------------------------------------
__global__ __launch_bounds__(256) void agg_kernel(const unsigned short* __restrict__ hprev,
                                                  const int* __restrict__ deg,
                                                  const int* __restrict__ bucket,
                                                  unsigned short* __restrict__ y, int n) {
    int wave = threadIdx.x >> 6, lane = threadIdx.x & 63;
    int n0 = (blockIdx.x * 4 + wave) * 2;
    if (n0 >= n) return;
    int n1 = n0 + 1;
    bool v1 = (n1 < n);
    int d0 = deg[n0]; if (d0 > CAP) d0 = CAP;
    int d1 = v1 ? deg[n1] : 0; if (d1 > CAP) d1 = CAP;
    int grp = lane >> 4, sub = lane & 15;
    const uint4* hp = (const uint4*)hprev;

    int idx0 = bucket[(size_t)n0 * CAP + lane];
    int idx1 = v1 ? bucket[(size_t)n1 * CAP + lane] : 0;

    float a0[8] = {0.f,0.f,0.f,0.f,0.f,0.f,0.f,0.f};
    float a1[8] = {0.f,0.f,0.f,0.f,0.f,0.f,0.f,0.f};
    int dmax = d0 > d1 ? d0 : d1;

    for (int t = 0; t < dmax; t += 16) {
        bool p0[4], p1[4];
        int r0[4], r1[4];
        #pragma unroll
        for (int q = 0; q < 4; ++q) {
            int e = t + q * 4 + grp;
            int s0 = __shfl(idx0, e & 63);
            int s1 = __shfl(idx1, e & 63);
            p0[q] = e < d0;
            p1[q] = e < d1;
            r0[q] = p0[q] ? s0 : n0;     // clamp to valid self row
            r1[q] = p1[q] ? s1 : n0;
        }
        uint4 w0[4], w1[4];
        #pragma unroll
        for (int q = 0; q < 4; ++q) {
            w0[q] = hp[(size_t)r0[q] * 16 + sub];
            w1[q] = hp[(size_t)r1[q] * 16 + sub];
        }
        #pragma unroll
        for (int q = 0; q < 4; ++q) {
            if (p0[q]) {
                uint4 v = w0[q];
                a0[0] += bf_lo(v.x); a0[1] += bf_hi(v.x);
                a0[2] += bf_lo(v.y); a0[3] += bf_hi(v.y);
                a0[4] += bf_lo(v.z); a0[5] += bf_hi(v.z);
                a0[6] += bf_lo(v.w); a0[7] += bf_hi(v.w);
            }
            if (p1[q]) {
                uint4 v = w1[q];
                a1[0] += bf_lo(v.x); a1[1] += bf_hi(v.x);
                a1[2] += bf_lo(v.y); a1[3] += bf_hi(v.y);
                a1[4] += bf_lo(v.z); a1[5] += bf_hi(v.z);
                a1[6] += bf_lo(v.w); a1[7] += bf_hi(v.w);
            }
        }
    }

    #pragma unroll
    for (int j = 0; j < 8; ++j) {
        a0[j] += __shfl_xor(a0[j], 16);
        a0[j] += __shfl_xor(a0[j], 32);
        a1[j] += __shfl_xor(a1[j], 16);
        a1[j] += __shfl_xor(a1[j], 32);
    }

    // self term (eps=0)
    uint4 s0v = hp[(size_t)n0 * 16 + sub];
    a0[0] += bf_lo(s0v.x); a0[1] += bf_hi(s0v.x);
    a0[2] += bf_lo(s0v.y); a0[3] += bf_hi(s0v.y);
    a0[4] += bf_lo(s0v.z); a0[5] += bf_hi(s0v.z);
    a0[6] += bf_lo(s0v.w); a0[7] += bf_hi(s0v.w);
    if (v1) {
        uint4 s1v = hp[(size_t)n1 * 16 + sub];
        a1[0] += bf_lo(s1v.x); a1[1] += bf_hi(s1v.x);
        a1[2] += bf_lo(s1v.y); a1[3] += bf_hi(s1v.y);
        a1[4] += bf_lo(s1v.z); a1[5] += bf_hi(s1v.z);
        a1[6] += bf_lo(s1v.w); a1[7] += bf_hi(s1v.w);
    }

    if (grp == 0) {
        uint4 o;
        o.x = (unsigned)f2bf(a0[0]) | ((unsigned)f2bf(a0[1]) << 16);
        o.y = (unsigned)f2bf(a0[2]) | ((unsigned)f2bf(a0[3]) << 16);
        o.z = (unsigned)f2bf(a0[4]) | ((unsigned)f2bf(a0[5]) << 16);
        o.w = (unsigned)f2bf(a0[6]) | ((unsigned)f2bf(a0[7]) << 16);
        ((uint4*)y)[(size_t)n0 * 16 + sub] = o;
        if (v1) {
            uint4 p;
            p.x = (unsigned)f2bf(a1[0]) | ((unsigned)f2bf(a1[1]) << 16);
            p.y = (unsigned)f2bf(a1[2]) | ((unsigned)f2bf(a1[3]) << 16);
            p.z = (unsigned)f2bf(a1[4]) | ((unsigned)f2bf(a1[5]) << 16);
            p.w = (unsigned)f2bf(a1[6]) | ((unsigned)f2bf(a1[7]) << 16);
            ((uint4*)y)[(size_t)n1 * 16 + sub] = p;
        }
    }
}

// ---------------------------------------------------------------------------
// Fused layer GEMM: h = relu((relu((A@W1)*a1+b1_) @ W2) + b2_) + fused pool.
// ---------------------------------------------------------------------------
__global__ __launch_bounds__(256) void layer_fused(const unsigned short* __restrict__ A,
                                                   const unsigned short* __restrict__ Wt1,
                                                   const unsigned short* __restrict__ Wt2,
                                                   const float* __restrict__ ea1,
                                                   const float* __restrict__ eb1,
                                                   const float* __restrict__ ea2,
                                                   const float* __restrict__ eb2,
                                                   const int* __restrict__ batch,
                                                   float* __restrict__ pooled, int loff,
                                                   unsigned short* __restrict__ outh, int n) {
    __shared__ unsigned short As[64][136];
    __shared__ unsigned short Ws[128][136];
    __shared__ int bgsh[64];
    int tid = threadIdx.x;
    int row0 = blockIdx.x * 64;
    int wave = tid >> 6, lane = tid & 63;
    int m0 = wave * 16;
    int lrow = lane & 15, lq = lane >> 4;

    #pragma unroll
    for (int i = 0; i < 4; ++i) {
        int idx = tid + i * 256;
        int r = idx >> 4, c = (idx & 15) * 8;
        ushort8 v = (ushort8)0;
        if (row0 + r < n) v = *(const ushort8*)&A[(size_t)(row0 + r) * D_FEAT + c];
        *(ushort8*)&As[r][c] = v;
    }
    #pragma unroll
    for (int i = 0; i < 8; ++i) {
        int idx = tid + i * 256;
        int r = idx >> 4, c = (idx & 15) * 8;
        *(ushort8*)&Ws[r][c] = *(const ushort8*)&Wt1[(size_t)r * D_FEAT + c];
    }
    if (tid < 64)
        bgsh[tid] = (row0 + tid < n) ? batch[row0 + tid] : -1;
    __syncthreads();

    // ---- GEMM 1 ----
    f32x4 acc[8] = {};
    #pragma unroll
    for (int t = 0; t < 4; ++t) {
        bf16x8 a = *(const bf16x8*)&As[m0 + lrow][t * 32 + lq * 8];
        #pragma unroll
        for (int nt = 0; nt < 8; ++nt) {
            bf16x8 b = *(const bf16x8*)&Ws[nt * 16 + lrow][t * 32 + lq * 8];
            acc[nt] = __builtin_amdgcn_mfma_f32_16x16x32_bf16(a, b, acc[nt], 0, 0, 0);
        }
    }
    __syncthreads();

    // epilogue 1 -> z (bf16) into As; stage Wt2 into Ws
    #pragma unroll
    for (int nt = 0; nt < 8; ++nt) {
        int col = nt * 16 + lrow;
        float al = ea1[col], be = eb1[col];
        #pragma unroll
        for (int r = 0; r < 4; ++r) {
            float v = fmaxf(fmaf(acc[nt][r], al, be), 0.f);
            As[m0 + lq * 4 + r][col] = f2bf(v);
        }
    }
    #pragma unroll
    for (int i = 0; i < 8; ++i) {
        int idx = tid + i * 256;
        int r = idx >> 4, c = (idx & 15) * 8;
        *(ushort8*)&Ws[r][c] = *(const ushort8*)&Wt2[(size_t)r * D_FEAT + c];
    }
    __syncthreads();

    // ---- GEMM 2 ----
    f32x4 acc2[8] = {};
    #pragma unroll
    for (int t = 0; t < 4; ++t) {
        bf16x8 a = *(const bf16x8*)&As[m0 + lrow][t * 32 + lq * 8];
        #pragma unroll
        for (int nt = 0; nt < 8; ++nt) {
            bf16x8 b = *(const bf16x8*)&Ws[nt * 16 + lrow][t * 32 + lq * 8];
            acc2[nt] = __builtin_amdgcn_mfma_f32_16x16x32_bf16(a, b, acc2[nt], 0, 0, 0);
        }
    }

    // epilogue 2 -> global h
    #pragma unroll
    for (int nt = 0; nt < 8; ++nt) {
        int col = nt * 16 + lrow;
        float al = ea2[col], be = eb2[col];
        #pragma unroll
        for (int r = 0; r < 4; ++r) {
            int grow = row0 + m0 + lq * 4 + r;
            if (grow < n) {
                float v = fmaxf(fmaf(acc2[nt][r], al, be), 0.f);
                outh[(size_t)grow * D_FEAT + col] = f2bf(v);
            }
        }
    }

    // ---- fused pooling ----
    __syncthreads();                       // all GEMM2 reads of Ws done
    float* Wsf = (float*)Ws;               // 64 x (stride 132) floats
    #pragma unroll
    for (int nt = 0; nt < 8; ++nt) {
        int col = nt * 16 + lrow;
        float al = ea2[col], be = eb2[col];
        #pragma unroll
        for (int r = 0; r < 4; ++r) {
            int lr = m0 + lq * 4 + r;
            float v = fmaxf(fmaf(acc2[nt][r], al, be), 0.f);
            Wsf[lr * 132 + col] = bf2f(f2bf(v));   // match bf16-rounded h
        }
    }
    __syncthreads();

    int c = tid & 127, half = tid >> 7;    // 2 halves x 32 rows each
    int rbeg = half * 32, rend = rbeg + 32;
    int cur = -1; float sum = 0.f;
    for (int r = rbeg; r < rend; ++r) {
        int g = bgsh[r];                   // uniform across the 128 col-threads
        if (g != cur) {
            if (cur >= 0) atomicAdd(&pooled[(size_t)cur * POOL_DIM + loff + c], sum);
            cur = g; sum = 0.f;
        }
        if (g >= 0) sum += Wsf[r * 132 + c];
    }
    if (cur >= 0) atomicAdd(&pooled[(size_t)cur * POOL_DIM + loff + c], sum);
}

// ---------------------------------------------------------------------------
// MLP head (fp32)
// ---------------------------------------------------------------------------
__global__ void fc1_kernel(const float* __restrict__ pooled, const float* __restrict__ W,
                           const float* __restrict__ b, float* __restrict__ out) {
    int idx = blockIdx.x * 256 + threadIdx.x;    // 512*384
    if (idx >= N_GRAPHS * POOL_DIM) return;
    int r = idx / POOL_DIM, c = idx % POOL_DIM;
    float s = b[c];
    const float* prow = pooled + (size_t)r * POOL_DIM;
    for (int k = 0; k < POOL_DIM; ++k)
        s = fmaf(prow[k], W[(size_t)k * POOL_DIM + c], s);
    out[idx] = fmaxf(s, 0.f);
}

__global__ void fc2_kernel(const float* __restrict__ fc1o, const float* __restrict__ W,
                           const float* __restrict__ b, float* __restrict__ out) {
    int idx = blockIdx.x * 256 + threadIdx.x;    // 512*10
    if (idx >= N_GRAPHS * N_CLASSES) return;
    int r = idx / N_CLASSES, c = idx % N_CLASSES;
    float s = b[c];
    const float* prow = fc1o + (size_t)r * POOL_DIM;
    for (int k = 0; k < POOL_DIM; ++k)
        s = fmaf(prow[k], W[(size_t)k * N_CLASSES + c], s);
    out[idx] = s;
}

// ---------------------------------------------------------------------------
extern "C" void kernel_launch(void* const* d_in, const int* in_sizes, int n_in,
                              void* d_out, int out_size, void* d_ws, size_t ws_size,
                              hipStream_t stream) {
    const float* x      = (const float*)d_in[0];
    const int*   ei     = (const int*)  d_in[1];
    const int*   batch  = (const int*)  d_in[2];
    const float* W1     = (const float*)d_in[3];
    const float* b1     = (const float*)d_in[4];
    const float* gamma  = (const float*)d_in[5];
    const float* beta   = (const float*)d_in[6];
    const float* rm     = (const float*)d_in[7];
    const float* rv     = (const float*)d_in[8];
    const float* W2     = (const float*)d_in[9];
    const float* b2     = (const float*)d_in[10];
    const float* lin1W  = (const float*)d_in[11];
    const float* lin1b  = (const float*)d_in[12];
    const float* lin2W  = (const float*)d_in[13];
    const float* lin2b  = (const float*)d_in[14];
    float* out = (float*)d_out;

    const int N = in_sizes[0] / D_FEAT;   // 50000
    const int E = in_sizes[1] / 2;        // 800000
    const int binCap = E / NBINS + 8192;  // bins ~Binomial(E,1/8), 27-sigma slack

    char* ws = (char*)d_ws;
    auto carve = [&](size_t bytes) {
        char* p = ws;
        ws += (bytes + 255) & ~(size_t)255;
        return p;
    };
    int*   cursor    = (int*)  carve((size_t)N * 4);
    int*   binCnt    = (int*)  carve((size_t)NBINS * 4);
    int*   bucket    = (int*)  carve((size_t)N * CAP * 4);
    int2*  pairs     = (int2*) carve((size_t)NBINS * binCap * 8);
    float* ea        = (float*)carve((size_t)2 * N_LAYERS * D_FEAT * 4);
    float* eb        = (float*)carve((size_t)2 * N_LAYERS * D_FEAT * 4);
    unsigned short* Wt   = (unsigned short*)carve((size_t)2 * N_LAYERS * D_FEAT * D_FEAT * 2);
    unsigned short* xb   = (unsigned short*)carve((size_t)N * D_FEAT * 2);
    unsigned short* ybuf = (unsigned short*)carve((size_t)N * D_FEAT * 2);
    unsigned short* hbuf = (unsigned short*)carve((size_t)N * D_FEAT * 2);
    float* pooled    = (float*)carve((size_t)N_GRAPHS * POOL_DIM * 4);
    float* fc1o      = (float*)carve((size_t)N_GRAPHS * POOL_DIM * 4);

    hipMemsetAsync(cursor, 0, (size_t)N * 4, stream);
    hipMemsetAsync(binCnt, 0, (size_t)NBINS * 4, stream);
    hipMemsetAsync(pooled, 0, (size_t)N_GRAPHS * POOL_DIM * 4, stream);
    bin_kernel<<<256, 256, 0, stream>>>(ei, E, N, pairs, binCap, binCnt);
    fill_v3<<<8 * 64, 256, 0, stream>>>(pairs, binCnt, binCap, cursor, bucket);
    prep_kernel<<<2, 256, 0, stream>>>(b1, gamma, beta, rm, rv, b2, ea, eb);
    cvt_x<<<(N * D_FEAT / 4 + 255) / 256, 256, 0, stream>>>(x, xb, N * D_FEAT / 4);
    cvt_w<<<(2 * N_LAYERS * D_FEAT * D_FEAT + 255) / 256, 256, 0, stream>>>(W1, W2, Wt);

    const unsigned short* hprev = xb;
    for (int l = 0; l < N_LAYERS; ++l) {
        agg_kernel<<<(N + 7) / 8, 256, 0, stream>>>(hprev, cursor, bucket, ybuf, N);
        layer_fused<<<(N + 63) / 64, 256, 0, stream>>>(ybuf,
                      Wt + (size_t)(2 * l) * D_FEAT * D_FEAT,
                      Wt + (size_t)(2 * l + 1) * D_FEAT * D_FEAT,
                      ea + (size_t)(2 * l) * D_FEAT,
                      eb + (size_t)(2 * l) * D_FEAT,
                      ea + (size_t)(2 * l + 1) * D_FEAT,
                      eb + (size_t)(2 * l + 1) * D_FEAT,
                      batch, pooled, l * D_FEAT, hbuf, N);
        hprev = hbuf;
    }
    fc1_kernel<<<(N_GRAPHS * POOL_DIM + 255) / 256, 256, 0, stream>>>(pooled, lin1W, lin1b, fc1o);
    fc2_kernel<<<(N_GRAPHS * N_CLASSES + 255) / 256, 256, 0, stream>>>(fc1o, lin2W, lin2b, out);
}

// Round 9
// 371.980 us; speedup vs baseline: 1.1387x; 1.0163x over previous
//
#include <hip/hip_runtime.h>
#include <hip/hip_bf16.h>

// Problem constants: N=50000, E=800000, G=512, L=3, D=128
#define D_FEAT 128
#define N_GRAPHS 512
#define N_LAYERS 3
#define POOL_DIM (N_LAYERS * D_FEAT)   // 384
#define N_CLASSES 10
#define BN_EPS 1e-5f
#define CAP 64                         // fixed bucket capacity; P(deg>64) ~ 2e-18
#define NBINS 8
#define SLABCAP 768                    // per (bin,block) slab; mean 390, 13.5 sigma

// LESSON (r7): gather is latency-bound -> needs max occupancy + tiny footprint;
// GEMM needs 52KB LDS. Keep them separate kernels.
// LESSON (r3/r8): any scatter region written at <64B granularity by blocks on
// multiple XCDs gets ~16x writeback amplification. Give each block a private
// slab (this round's bin_kernel) or partition writers by XCD (fill).

typedef __attribute__((ext_vector_type(8))) short bf16x8;
typedef __attribute__((ext_vector_type(8))) unsigned short ushort8;
typedef __attribute__((ext_vector_type(4))) float f32x4;

__device__ __forceinline__ unsigned short f2bf(float f) {
    unsigned u = __builtin_bit_cast(unsigned, f);
    u += 0x7FFFu + ((u >> 16) & 1u);          // round-to-nearest-even
    return (unsigned short)(u >> 16);
}
__device__ __forceinline__ float bf2f(unsigned short h) {
    unsigned u = ((unsigned)h) << 16;
    return __builtin_bit_cast(float, u);
}
__device__ __forceinline__ float bf_lo(unsigned u) {
    return __builtin_bit_cast(float, u << 16);
}
__device__ __forceinline__ float bf_hi(unsigned u) {
    return __builtin_bit_cast(float, u & 0xffff0000u);
}

// ---------------------------------------------------------------------------
// Pass A: single-pass radix partition into per-(bin,block) PRIVATE slabs.
// Block-local LDS cursors; every 64B output line owned by exactly one block.
// ---------------------------------------------------------------------------
__global__ __launch_bounds__(256) void bin_kernel(const int* __restrict__ ei, int E, int N,
                                                  int2* __restrict__ pairs,
                                                  int* __restrict__ cnts) {
    __shared__ int loc[NBINS];
    int per = (E + gridDim.x - 1) / gridDim.x;
    int e0 = blockIdx.x * per;
    int e1 = e0 + per; if (e1 > E) e1 = E;
    int span = (N + NBINS - 1) / NBINS;
    if (threadIdx.x < NBINS) loc[threadIdx.x] = 0;
    __syncthreads();
    for (int e = e0 + threadIdx.x; e < e1; e += 256) {
        int dst = ei[E + e];
        int src = ei[e];
        int b = dst / span;
        int p = atomicAdd(&loc[b], 1);
        if (p < SLABCAP)
            pairs[((size_t)(b * 256 + blockIdx.x)) * SLABCAP + p] = make_int2(src, dst);
    }
    __syncthreads();
    if (threadIdx.x < NBINS)
        cnts[threadIdx.x * 256 + blockIdx.x] = loc[threadIdx.x];
}

// ---------------------------------------------------------------------------
// Pass B: per-range fill. blockIdx%8 = dst-range = XCD (CP round-robin):
// cursor atomics + bucket scatter stay in one XCD's L2. Dense slab reads.
// ---------------------------------------------------------------------------
__global__ __launch_bounds__(256) void fill_v3(const int2* __restrict__ pairs,
                                               const int* __restrict__ cnts,
                                               int* __restrict__ cursor,
                                               int* __restrict__ bucket) {
    int r = blockIdx.x & 7;
    int chunk = blockIdx.x >> 3;              // 0..63
    #pragma unroll
    for (int s = 0; s < 4; ++s) {
        int blk = chunk * 4 + s;              // 0..255
        int cnt = cnts[r * 256 + blk];
        if (cnt > SLABCAP) cnt = SLABCAP;
        const int2* slab = pairs + (size_t)(r * 256 + blk) * SLABCAP;
        for (int p = threadIdx.x; p < cnt; p += 256) {
            int2 pr = slab[p];
            int pos = atomicAdd(&cursor[pr.y], 1);
            if (pos < CAP) bucket[(size_t)pr.y * CAP + pos] = pr.x;
        }
    }
}

// ---------------------------------------------------------------------------
// Merged setup: cvt_x | cvt_w(+transpose) | prep(BN fold) | zero cursor | zero
// pooled — one branched grid, replaces 4 dispatches + 2 memsets.
// ---------------------------------------------------------------------------
__global__ __launch_bounds__(256) void setup_kernel(
        const float* __restrict__ x, unsigned short* __restrict__ xb,
        const float* __restrict__ W1, const float* __restrict__ W2,
        unsigned short* __restrict__ Wt,
        const float* __restrict__ b1, const float* __restrict__ gamma,
        const float* __restrict__ beta, const float* __restrict__ rm,
        const float* __restrict__ rv, const float* __restrict__ b2,
        float* __restrict__ ea, float* __restrict__ eb,
        int* __restrict__ cursor, float* __restrict__ pooled,
        int N, int n4, int B0, int B1, int B2, int B3) {
    int b = blockIdx.x, tid = threadIdx.x;
    if (b < B0) {                                     // cvt_x: fp32 -> bf16
        int i = b * 256 + tid;
        if (i < n4) {
            float4 v = ((const float4*)x)[i];
            ushort4 o;
            o.x = f2bf(v.x); o.y = f2bf(v.y); o.z = f2bf(v.z); o.w = f2bf(v.w);
            ((ushort4*)xb)[i] = o;
        }
    } else if (b < B1) {                              // cvt_w: transpose->bf16
        int idx = (b - B0) * 256 + tid;               // exactly 2*L*128*128
        int slot = idx >> 14;
        int r = (idx >> 7) & 127;                     // n
        int c = idx & 127;                            // k
        int l = slot >> 1;
        const float* W = (slot & 1) ? W2 : W1;
        Wt[idx] = f2bf(W[(size_t)l * D_FEAT * D_FEAT + (size_t)c * D_FEAT + r]);
    } else if (b < B2) {                              // prep: fold BN+bias
        int i = (b - B1) * 256 + tid;
        if (i < N_LAYERS * D_FEAT) {
            int l = i >> 7, c = i & 127;
            float s = gamma[i] * rsqrtf(rv[i] + BN_EPS);
            ea[(2 * l) * D_FEAT + c] = s;
            eb[(2 * l) * D_FEAT + c] = (b1[i] - rm[i]) * s + beta[i];
            ea[(2 * l + 1) * D_FEAT + c] = 1.0f;
            eb[(2 * l + 1) * D_FEAT + c] = b2[i];
        }
    } else if (b < B3) {                              // zero cursor
        int i = (b - B2) * 256 + tid;
        if (i < N) cursor[i] = 0;
    } else {                                          // zero pooled
        int i = (b - B3) * 256 + tid;
        if (i < N_GRAPHS * POOL_DIM) pooled[i] = 0.f;
    }
}

// ---------------------------------------------------------------------------
// Aggregation: one wave per TWO nodes, zero LDS, high occupancy, software-
// pipelined: issue chunk t+16's 8 unconditional dwordx4 gathers BEFORE
// accumulating chunk t, so the waitcnt on chunk t drains while t+16 flies.
// 4 lane-groups of 16 each fetch a full 256B row; fp32 accum; butterfly.
// ---------------------------------------------------------------------------
__global__ __launch_bounds__(256) void agg_kernel(const unsigned short* __restrict__ hprev,
                                                  const int* __restrict__ deg,
                                                  const int* __restrict__ bucket,
                                                  unsigned short* __restrict__ y, int n) {
    int wave = threadIdx.x >> 6, lane = threadIdx.x & 63;
    int n0 = (blockIdx.x * 4 + wave) * 2;
    if (n0 >= n) return;
    int n1 = n0 + 1;
    bool v1 = (n1 < n);
    int d0 = deg[n0]; if (d0 > CAP) d0 = CAP;
    int d1 = v1 ? deg[n1] : 0; if (d1 > CAP) d1 = CAP;
    int grp = lane >> 4, sub = lane & 15;
    const uint4* hp = (const uint4*)hprev;

    int idx0 = bucket[(size_t)n0 * CAP + lane];
    int idx1 = v1 ? bucket[(size_t)n1 * CAP + lane] : 0;

    float a0[8] = {0.f,0.f,0.f,0.f,0.f,0.f,0.f,0.f};
    float a1[8] = {0.f,0.f,0.f,0.f,0.f,0.f,0.f,0.f};
    int dmax = d0 > d1 ? d0 : d1;

    auto issue = [&](int t, bool (&p0)[4], bool (&p1)[4],
                     uint4 (&w0)[4], uint4 (&w1)[4]) {
        #pragma unroll
        for (int q = 0; q < 4; ++q) {
            int e = t + q * 4 + grp;
            int s0 = __shfl(idx0, e & 63);
            int s1 = __shfl(idx1, e & 63);
            p0[q] = e < d0;
            p1[q] = e < d1;
            int r0 = p0[q] ? s0 : n0;     // clamp to valid self row
            int r1 = p1[q] ? s1 : n0;
            w0[q] = hp[(size_t)r0 * 16 + sub];
            w1[q] = hp[(size_t)r1 * 16 + sub];
        }
    };
    auto accum = [&](bool (&p0)[4], bool (&p1)[4],
                     uint4 (&w0)[4], uint4 (&w1)[4]) {
        #pragma unroll
        for (int q = 0; q < 4; ++q) {
            if (p0[q]) {
                uint4 v = w0[q];
                a0[0] += bf_lo(v.x); a0[1] += bf_hi(v.x);
                a0[2] += bf_lo(v.y); a0[3] += bf_hi(v.y);
                a0[4] += bf_lo(v.z); a0[5] += bf_hi(v.z);
                a0[6] += bf_lo(v.w); a0[7] += bf_hi(v.w);
            }
            if (p1[q]) {
                uint4 v = w1[q];
                a1[0] += bf_lo(v.x); a1[1] += bf_hi(v.x);
                a1[2] += bf_lo(v.y); a1[3] += bf_hi(v.y);
                a1[4] += bf_lo(v.z); a1[5] += bf_hi(v.z);
                a1[6] += bf_lo(v.w); a1[7] += bf_hi(v.w);
            }
        }
    };

    if (dmax > 0) {
        bool cp0[4], cp1[4];
        uint4 cw0[4], cw1[4];
        issue(0, cp0, cp1, cw0, cw1);
        for (int t = 16; t < dmax; t += 16) {
            bool np0[4], np1[4];
            uint4 nw0[4], nw1[4];
            issue(t, np0, np1, nw0, nw1);     // next chunk in flight...
            accum(cp0, cp1, cw0, cw1);        // ...while current drains
            #pragma unroll
            for (int q = 0; q < 4; ++q) {
                cp0[q] = np0[q]; cp1[q] = np1[q];
                cw0[q] = nw0[q]; cw1[q] = nw1[q];
            }
        }
        accum(cp0, cp1, cw0, cw1);
    }

    #pragma unroll
    for (int j = 0; j < 8; ++j) {
        a0[j] += __shfl_xor(a0[j], 16);
        a0[j] += __shfl_xor(a0[j], 32);
        a1[j] += __shfl_xor(a1[j], 16);
        a1[j] += __shfl_xor(a1[j], 32);
    }

    // self term (eps=0)
    uint4 s0v = hp[(size_t)n0 * 16 + sub];
    a0[0] += bf_lo(s0v.x); a0[1] += bf_hi(s0v.x);
    a0[2] += bf_lo(s0v.y); a0[3] += bf_hi(s0v.y);
    a0[4] += bf_lo(s0v.z); a0[5] += bf_hi(s0v.z);
    a0[6] += bf_lo(s0v.w); a0[7] += bf_hi(s0v.w);
    if (v1) {
        uint4 s1v = hp[(size_t)n1 * 16 + sub];
        a1[0] += bf_lo(s1v.x); a1[1] += bf_hi(s1v.x);
        a1[2] += bf_lo(s1v.y); a1[3] += bf_hi(s1v.y);
        a1[4] += bf_lo(s1v.z); a1[5] += bf_hi(s1v.z);
        a1[6] += bf_lo(s1v.w); a1[7] += bf_hi(s1v.w);
    }

    if (grp == 0) {
        uint4 o;
        o.x = (unsigned)f2bf(a0[0]) | ((unsigned)f2bf(a0[1]) << 16);
        o.y = (unsigned)f2bf(a0[2]) | ((unsigned)f2bf(a0[3]) << 16);
        o.z = (unsigned)f2bf(a0[4]) | ((unsigned)f2bf(a0[5]) << 16);
        o.w = (unsigned)f2bf(a0[6]) | ((unsigned)f2bf(a0[7]) << 16);
        ((uint4*)y)[(size_t)n0 * 16 + sub] = o;
        if (v1) {
            uint4 p;
            p.x = (unsigned)f2bf(a1[0]) | ((unsigned)f2bf(a1[1]) << 16);
            p.y = (unsigned)f2bf(a1[2]) | ((unsigned)f2bf(a1[3]) << 16);
            p.z = (unsigned)f2bf(a1[4]) | ((unsigned)f2bf(a1[5]) << 16);
            p.w = (unsigned)f2bf(a1[6]) | ((unsigned)f2bf(a1[7]) << 16);
            ((uint4*)y)[(size_t)n1 * 16 + sub] = p;
        }
    }
}

// ---------------------------------------------------------------------------
// Fused layer GEMM: h = relu((relu((A@W1)*a1+b1_) @ W2) + b2_) + fused pool.
// ---------------------------------------------------------------------------
__global__ __launch_bounds__(256) void layer_fused(const unsigned short* __restrict__ A,
                                                   const unsigned short* __restrict__ Wt1,
                                                   const unsigned short* __restrict__ Wt2,
                                                   const float* __restrict__ ea1,
                                                   const float* __restrict__ eb1,
                                                   const float* __restrict__ ea2,
                                                   const float* __restrict__ eb2,
                                                   const int* __restrict__ batch,
                                                   float* __restrict__ pooled, int loff,
                                                   unsigned short* __restrict__ outh, int n) {
    __shared__ unsigned short As[64][136];
    __shared__ unsigned short Ws[128][136];
    __shared__ int bgsh[64];
    int tid = threadIdx.x;
    int row0 = blockIdx.x * 64;
    int wave = tid >> 6, lane = tid & 63;
    int m0 = wave * 16;
    int lrow = lane & 15, lq = lane >> 4;

    #pragma unroll
    for (int i = 0; i < 4; ++i) {
        int idx = tid + i * 256;
        int r = idx >> 4, c = (idx & 15) * 8;
        ushort8 v = (ushort8)0;
        if (row0 + r < n) v = *(const ushort8*)&A[(size_t)(row0 + r) * D_FEAT + c];
        *(ushort8*)&As[r][c] = v;
    }
    #pragma unroll
    for (int i = 0; i < 8; ++i) {
        int idx = tid + i * 256;
        int r = idx >> 4, c = (idx & 15) * 8;
        *(ushort8*)&Ws[r][c] = *(const ushort8*)&Wt1[(size_t)r * D_FEAT + c];
    }
    if (tid < 64)
        bgsh[tid] = (row0 + tid < n) ? batch[row0 + tid] : -1;
    __syncthreads();

    // ---- GEMM 1 ----
    f32x4 acc[8] = {};
    #pragma unroll
    for (int t = 0; t < 4; ++t) {
        bf16x8 a = *(const bf16x8*)&As[m0 + lrow][t * 32 + lq * 8];
        #pragma unroll
        for (int nt = 0; nt < 8; ++nt) {
            bf16x8 b = *(const bf16x8*)&Ws[nt * 16 + lrow][t * 32 + lq * 8];
            acc[nt] = __builtin_amdgcn_mfma_f32_16x16x32_bf16(a, b, acc[nt], 0, 0, 0);
        }
    }
    __syncthreads();

    // epilogue 1 -> z (bf16) into As; stage Wt2 into Ws
    #pragma unroll
    for (int nt = 0; nt < 8; ++nt) {
        int col = nt * 16 + lrow;
        float al = ea1[col], be = eb1[col];
        #pragma unroll
        for (int r = 0; r < 4; ++r) {
            float v = fmaxf(fmaf(acc[nt][r], al, be), 0.f);
            As[m0 + lq * 4 + r][col] = f2bf(v);
        }
    }
    #pragma unroll
    for (int i = 0; i < 8; ++i) {
        int idx = tid + i * 256;
        int r = idx >> 4, c = (idx & 15) * 8;
        *(ushort8*)&Ws[r][c] = *(const ushort8*)&Wt2[(size_t)r * D_FEAT + c];
    }
    __syncthreads();

    // ---- GEMM 2 ----
    f32x4 acc2[8] = {};
    #pragma unroll
    for (int t = 0; t < 4; ++t) {
        bf16x8 a = *(const bf16x8*)&As[m0 + lrow][t * 32 + lq * 8];
        #pragma unroll
        for (int nt = 0; nt < 8; ++nt) {
            bf16x8 b = *(const bf16x8*)&Ws[nt * 16 + lrow][t * 32 + lq * 8];
            acc2[nt] = __builtin_amdgcn_mfma_f32_16x16x32_bf16(a, b, acc2[nt], 0, 0, 0);
        }
    }

    // epilogue 2 -> global h
    #pragma unroll
    for (int nt = 0; nt < 8; ++nt) {
        int col = nt * 16 + lrow;
        float al = ea2[col], be = eb2[col];
        #pragma unroll
        for (int r = 0; r < 4; ++r) {
            int grow = row0 + m0 + lq * 4 + r;
            if (grow < n) {
                float v = fmaxf(fmaf(acc2[nt][r], al, be), 0.f);
                outh[(size_t)grow * D_FEAT + col] = f2bf(v);
            }
        }
    }

    // ---- fused pooling ----
    __syncthreads();                       // all GEMM2 reads of Ws done
    float* Wsf = (float*)Ws;               // 64 x (stride 132) floats
    #pragma unroll
    for (int nt = 0; nt < 8; ++nt) {
        int col = nt * 16 + lrow;
        float al = ea2[col], be = eb2[col];
        #pragma unroll
        for (int r = 0; r < 4; ++r) {
            int lr = m0 + lq * 4 + r;
            float v = fmaxf(fmaf(acc2[nt][r], al, be), 0.f);
            Wsf[lr * 132 + col] = bf2f(f2bf(v));   // match bf16-rounded h
        }
    }
    __syncthreads();

    int c = tid & 127, half = tid >> 7;    // 2 halves x 32 rows each
    int rbeg = half * 32, rend = rbeg + 32;
    int cur = -1; float sum = 0.f;
    for (int r = rbeg; r < rend; ++r) {
        int g = bgsh[r];                   // uniform across the 128 col-threads
        if (g != cur) {
            if (cur >= 0) atomicAdd(&pooled[(size_t)cur * POOL_DIM + loff + c], sum);
            cur = g; sum = 0.f;
        }
        if (g >= 0) sum += Wsf[r * 132 + c];
    }
    if (cur >= 0) atomicAdd(&pooled[(size_t)cur * POOL_DIM + loff + c], sum);
}

// ---------------------------------------------------------------------------
// MLP head (fp32)
// ---------------------------------------------------------------------------
__global__ void fc1_kernel(const float* __restrict__ pooled, const float* __restrict__ W,
                           const float* __restrict__ b, float* __restrict__ out) {
    int idx = blockIdx.x * 256 + threadIdx.x;    // 512*384
    if (idx >= N_GRAPHS * POOL_DIM) return;
    int r = idx / POOL_DIM, c = idx % POOL_DIM;
    float s = b[c];
    const float* prow = pooled + (size_t)r * POOL_DIM;
    for (int k = 0; k < POOL_DIM; ++k)
        s = fmaf(prow[k], W[(size_t)k * POOL_DIM + c], s);
    out[idx] = fmaxf(s, 0.f);
}

__global__ void fc2_kernel(const float* __restrict__ fc1o, const float* __restrict__ W,
                           const float* __restrict__ b, float* __restrict__ out) {
    int idx = blockIdx.x * 256 + threadIdx.x;    // 512*10
    if (idx >= N_GRAPHS * N_CLASSES) return;
    int r = idx / N_CLASSES, c = idx % N_CLASSES;
    float s = b[c];
    const float* prow = fc1o + (size_t)r * POOL_DIM;
    for (int k = 0; k < POOL_DIM; ++k)
        s = fmaf(prow[k], W[(size_t)k * N_CLASSES + c], s);
    out[idx] = s;
}

// ---------------------------------------------------------------------------
extern "C" void kernel_launch(void* const* d_in, const int* in_sizes, int n_in,
                              void* d_out, int out_size, void* d_ws, size_t ws_size,
                              hipStream_t stream) {
    const float* x      = (const float*)d_in[0];
    const int*   ei     = (const int*)  d_in[1];
    const int*   batch  = (const int*)  d_in[2];
    const float* W1     = (const float*)d_in[3];
    const float* b1     = (const float*)d_in[4];
    const float* gamma  = (const float*)d_in[5];
    const float* beta   = (const float*)d_in[6];
    const float* rm     = (const float*)d_in[7];
    const float* rv     = (const float*)d_in[8];
    const float* W2     = (const float*)d_in[9];
    const float* b2     = (const float*)d_in[10];
    const float* lin1W  = (const float*)d_in[11];
    const float* lin1b  = (const float*)d_in[12];
    const float* lin2W  = (const float*)d_in[13];
    const float* lin2b  = (const float*)d_in[14];
    float* out = (float*)d_out;

    const int N = in_sizes[0] / D_FEAT;   // 50000
    const int E = in_sizes[1] / 2;        // 800000

    char* ws = (char*)d_ws;
    auto carve = [&](size_t bytes) {
        char* p = ws;
        ws += (bytes + 255) & ~(size_t)255;
        return p;
    };
    int*   cursor    = (int*)  carve((size_t)N * 4);
    int*   cnts      = (int*)  carve((size_t)NBINS * 256 * 4);
    int*   bucket    = (int*)  carve((size_t)N * CAP * 4);
    int2*  pairs     = (int2*) carve((size_t)NBINS * 256 * SLABCAP * 8);
    float* ea        = (float*)carve((size_t)2 * N_LAYERS * D_FEAT * 4);
    float* eb        = (float*)carve((size_t)2 * N_LAYERS * D_FEAT * 4);
    unsigned short* Wt   = (unsigned short*)carve((size_t)2 * N_LAYERS * D_FEAT * D_FEAT * 2);
    unsigned short* xb   = (unsigned short*)carve((size_t)N * D_FEAT * 2);
    unsigned short* ybuf = (unsigned short*)carve((size_t)N * D_FEAT * 2);
    unsigned short* hbuf = (unsigned short*)carve((size_t)N * D_FEAT * 2);
    float* pooled    = (float*)carve((size_t)N_GRAPHS * POOL_DIM * 4);
    float* fc1o      = (float*)carve((size_t)N_GRAPHS * POOL_DIM * 4);

    // merged setup grid layout
    const int n4 = N * D_FEAT / 4;
    const int B0 = (n4 + 255) / 256;                          // cvt_x
    const int B1 = B0 + (2 * N_LAYERS * D_FEAT * D_FEAT) / 256; // cvt_w (exact)
    const int B2 = B1 + 2;                                    // prep
    const int B3 = B2 + (N + 255) / 256;                      // cursor zero
    const int B4 = B3 + (N_GRAPHS * POOL_DIM + 255) / 256;    // pooled zero

    setup_kernel<<<B4, 256, 0, stream>>>(x, xb, W1, W2, Wt, b1, gamma, beta,
                                         rm, rv, b2, ea, eb, cursor, pooled,
                                         N, n4, B0, B1, B2, B3);
    bin_kernel<<<256, 256, 0, stream>>>(ei, E, N, pairs, cnts);
    fill_v3<<<8 * 64, 256, 0, stream>>>(pairs, cnts, cursor, bucket);

    const unsigned short* hprev = xb;
    for (int l = 0; l < N_LAYERS; ++l) {
        agg_kernel<<<(N + 7) / 8, 256, 0, stream>>>(hprev, cursor, bucket, ybuf, N);
        layer_fused<<<(N + 63) / 64, 256, 0, stream>>>(ybuf,
                      Wt + (size_t)(2 * l) * D_FEAT * D_FEAT,
                      Wt + (size_t)(2 * l + 1) * D_FEAT * D_FEAT,
                      ea + (size_t)(2 * l) * D_FEAT,
                      eb + (size_t)(2 * l) * D_FEAT,
                      ea + (size_t)(2 * l + 1) * D_FEAT,
                      eb + (size_t)(2 * l + 1) * D_FEAT,
                      batch, pooled, l * D_FEAT, hbuf, N);
        hprev = hbuf;
    }
    fc1_kernel<<<(N_GRAPHS * POOL_DIM + 255) / 256, 256, 0, stream>>>(pooled, lin1W, lin1b, fc1o);
    fc2_kernel<<<(N_GRAPHS * N_CLASSES + 255) / 256, 256, 0, stream>>>(fc1o, lin2W, lin2b, out);
}

// Round 10
// 349.965 us; speedup vs baseline: 1.2103x; 1.0629x over previous
//
#include <hip/hip_runtime.h>
#include <hip/hip_bf16.h>

// Problem constants: N=50000, E=800000, G=512, L=3, D=128
#define D_FEAT 128
#define N_GRAPHS 512
#define N_LAYERS 3
#define POOL_DIM (N_LAYERS * D_FEAT)   // 384
#define N_CLASSES 10
#define BN_EPS 1e-5f
#define CAP 64                         // fixed bucket capacity; P(deg>64) ~ 2e-18
#define NBINS 8
#define SLABCAP 768                    // per (bin,block) slab; mean 390, 13.5 sigma

// LESSON (r7): gather is latency-bound -> needs max occupancy + tiny footprint;
// GEMM needs 52KB LDS. Keep them separate kernels.
// LESSON (r3/r8): any scatter region written at <64B granularity by blocks on
// multiple XCDs gets ~16x writeback amplification. Private slabs / XCD
// partitioning fix it.

typedef __attribute__((ext_vector_type(8))) short bf16x8;
typedef __attribute__((ext_vector_type(8))) unsigned short ushort8;
typedef __attribute__((ext_vector_type(4))) float f32x4;

__device__ __forceinline__ unsigned short f2bf(float f) {
    unsigned u = __builtin_bit_cast(unsigned, f);
    u += 0x7FFFu + ((u >> 16) & 1u);          // round-to-nearest-even
    return (unsigned short)(u >> 16);
}
__device__ __forceinline__ float bf2f(unsigned short h) {
    unsigned u = ((unsigned)h) << 16;
    return __builtin_bit_cast(float, u);
}
__device__ __forceinline__ float bf_lo(unsigned u) {
    return __builtin_bit_cast(float, u << 16);
}
__device__ __forceinline__ float bf_hi(unsigned u) {
    return __builtin_bit_cast(float, u & 0xffff0000u);
}

// ---------------------------------------------------------------------------
// Merged setup: cvt_x | cvt_w | prep | zero cursor | zero pooled | BIN.
// Bin region: single-pass radix partition into per-(bin,block) PRIVATE slabs
// (block-local LDS cursors; every 64B line owned by one block).
// ---------------------------------------------------------------------------
__global__ __launch_bounds__(256) void setup_kernel(
        const float* __restrict__ x, unsigned short* __restrict__ xb,
        const float* __restrict__ W1, const float* __restrict__ W2,
        unsigned short* __restrict__ Wt,
        const float* __restrict__ b1, const float* __restrict__ gamma,
        const float* __restrict__ beta, const float* __restrict__ rm,
        const float* __restrict__ rv, const float* __restrict__ b2,
        float* __restrict__ ea, float* __restrict__ eb,
        int* __restrict__ cursor, float* __restrict__ pooled,
        const int* __restrict__ ei, int2* __restrict__ pairs,
        int* __restrict__ cnts, int E,
        int N, int n4, int B0, int B1, int B2, int B3, int B4) {
    int b = blockIdx.x, tid = threadIdx.x;
    if (b < B0) {                                     // cvt_x: fp32 -> bf16
        int i = b * 256 + tid;
        if (i < n4) {
            float4 v = ((const float4*)x)[i];
            ushort4 o;
            o.x = f2bf(v.x); o.y = f2bf(v.y); o.z = f2bf(v.z); o.w = f2bf(v.w);
            ((ushort4*)xb)[i] = o;
        }
    } else if (b < B1) {                              // cvt_w: transpose->bf16
        int idx = (b - B0) * 256 + tid;               // exactly 2*L*128*128
        int slot = idx >> 14;
        int r = (idx >> 7) & 127;                     // n
        int c = idx & 127;                            // k
        int l = slot >> 1;
        const float* W = (slot & 1) ? W2 : W1;
        Wt[idx] = f2bf(W[(size_t)l * D_FEAT * D_FEAT + (size_t)c * D_FEAT + r]);
    } else if (b < B2) {                              // prep: fold BN+bias
        int i = (b - B1) * 256 + tid;
        if (i < N_LAYERS * D_FEAT) {
            int l = i >> 7, c = i & 127;
            float s = gamma[i] * rsqrtf(rv[i] + BN_EPS);
            ea[(2 * l) * D_FEAT + c] = s;
            eb[(2 * l) * D_FEAT + c] = (b1[i] - rm[i]) * s + beta[i];
            ea[(2 * l + 1) * D_FEAT + c] = 1.0f;
            eb[(2 * l + 1) * D_FEAT + c] = b2[i];
        }
    } else if (b < B3) {                              // zero cursor
        int i = (b - B2) * 256 + tid;
        if (i < N) cursor[i] = 0;
    } else if (b < B4) {                              // zero pooled
        int i = (b - B3) * 256 + tid;
        if (i < N_GRAPHS * POOL_DIM) pooled[i] = 0.f;
    } else {                                          // bin: radix partition
        __shared__ int loc[NBINS];
        int bb = b - B4;                              // 0..255
        int per = (E + 255) / 256;
        int e0 = bb * per;
        int e1 = e0 + per; if (e1 > E) e1 = E;
        int span = (N + NBINS - 1) / NBINS;
        if (tid < NBINS) loc[tid] = 0;
        __syncthreads();
        for (int e = e0 + tid; e < e1; e += 256) {
            int dst = ei[E + e];
            int src = ei[e];
            int bin = dst / span;
            int p = atomicAdd(&loc[bin], 1);
            if (p < SLABCAP)
                pairs[((size_t)(bin * 256 + bb)) * SLABCAP + p] = make_int2(src, dst);
        }
        __syncthreads();
        if (tid < NBINS)
            cnts[tid * 256 + bb] = loc[tid];
    }
}

// ---------------------------------------------------------------------------
// Fill: blockIdx%8 = dst-range = XCD (CP round-robin): cursor atomics +
// bucket scatter stay in one XCD's L2. Dense slab reads.
// ---------------------------------------------------------------------------
__global__ __launch_bounds__(256) void fill_v3(const int2* __restrict__ pairs,
                                               const int* __restrict__ cnts,
                                               int* __restrict__ cursor,
                                               int* __restrict__ bucket) {
    int r = blockIdx.x & 7;
    int chunk = blockIdx.x >> 3;              // 0..63
    #pragma unroll
    for (int s = 0; s < 4; ++s) {
        int blk = chunk * 4 + s;              // 0..255
        int cnt = cnts[r * 256 + blk];
        if (cnt > SLABCAP) cnt = SLABCAP;
        const int2* slab = pairs + (size_t)(r * 256 + blk) * SLABCAP;
        for (int p = threadIdx.x; p < cnt; p += 256) {
            int2 pr = slab[p];
            int pos = atomicAdd(&cursor[pr.y], 1);
            if (pos < CAP) bucket[(size_t)pr.y * CAP + pos] = pr.x;
        }
    }
}

// ---------------------------------------------------------------------------
// Aggregation: one wave per TWO nodes, zero LDS, software-pipelined chunks;
// self-row loads hoisted ahead of the loop so their latency drains under it.
// ---------------------------------------------------------------------------
__global__ __launch_bounds__(256) void agg_kernel(const unsigned short* __restrict__ hprev,
                                                  const int* __restrict__ deg,
                                                  const int* __restrict__ bucket,
                                                  unsigned short* __restrict__ y, int n) {
    int wave = threadIdx.x >> 6, lane = threadIdx.x & 63;
    int n0 = (blockIdx.x * 4 + wave) * 2;
    if (n0 >= n) return;
    int n1 = n0 + 1;
    bool v1 = (n1 < n);
    int d0 = deg[n0]; if (d0 > CAP) d0 = CAP;
    int d1 = v1 ? deg[n1] : 0; if (d1 > CAP) d1 = CAP;
    int grp = lane >> 4, sub = lane & 15;
    const uint4* hp = (const uint4*)hprev;

    int idx0 = bucket[(size_t)n0 * CAP + lane];
    int idx1 = v1 ? bucket[(size_t)n1 * CAP + lane] : 0;

    // hoist self loads: issue now, consume after the loop
    uint4 s0v = hp[(size_t)n0 * 16 + sub];
    uint4 s1v = v1 ? hp[(size_t)n1 * 16 + sub] : make_uint4(0u, 0u, 0u, 0u);

    float a0[8] = {0.f,0.f,0.f,0.f,0.f,0.f,0.f,0.f};
    float a1[8] = {0.f,0.f,0.f,0.f,0.f,0.f,0.f,0.f};
    int dmax = d0 > d1 ? d0 : d1;

    auto issue = [&](int t, bool (&p0)[4], bool (&p1)[4],
                     uint4 (&w0)[4], uint4 (&w1)[4]) {
        #pragma unroll
        for (int q = 0; q < 4; ++q) {
            int e = t + q * 4 + grp;
            int s0 = __shfl(idx0, e & 63);
            int s1 = __shfl(idx1, e & 63);
            p0[q] = e < d0;
            p1[q] = e < d1;
            int r0 = p0[q] ? s0 : n0;     // clamp to valid self row
            int r1 = p1[q] ? s1 : n0;
            w0[q] = hp[(size_t)r0 * 16 + sub];
            w1[q] = hp[(size_t)r1 * 16 + sub];
        }
    };
    auto accum = [&](bool (&p0)[4], bool (&p1)[4],
                     uint4 (&w0)[4], uint4 (&w1)[4]) {
        #pragma unroll
        for (int q = 0; q < 4; ++q) {
            if (p0[q]) {
                uint4 v = w0[q];
                a0[0] += bf_lo(v.x); a0[1] += bf_hi(v.x);
                a0[2] += bf_lo(v.y); a0[3] += bf_hi(v.y);
                a0[4] += bf_lo(v.z); a0[5] += bf_hi(v.z);
                a0[6] += bf_lo(v.w); a0[7] += bf_hi(v.w);
            }
            if (p1[q]) {
                uint4 v = w1[q];
                a1[0] += bf_lo(v.x); a1[1] += bf_hi(v.x);
                a1[2] += bf_lo(v.y); a1[3] += bf_hi(v.y);
                a1[4] += bf_lo(v.z); a1[5] += bf_hi(v.z);
                a1[6] += bf_lo(v.w); a1[7] += bf_hi(v.w);
            }
        }
    };

    if (dmax > 0) {
        bool cp0[4], cp1[4];
        uint4 cw0[4], cw1[4];
        issue(0, cp0, cp1, cw0, cw1);
        for (int t = 16; t < dmax; t += 16) {
            bool np0[4], np1[4];
            uint4 nw0[4], nw1[4];
            issue(t, np0, np1, nw0, nw1);     // next chunk in flight...
            accum(cp0, cp1, cw0, cw1);        // ...while current drains
            #pragma unroll
            for (int q = 0; q < 4; ++q) {
                cp0[q] = np0[q]; cp1[q] = np1[q];
                cw0[q] = nw0[q]; cw1[q] = nw1[q];
            }
        }
        accum(cp0, cp1, cw0, cw1);
    }

    #pragma unroll
    for (int j = 0; j < 8; ++j) {
        a0[j] += __shfl_xor(a0[j], 16);
        a0[j] += __shfl_xor(a0[j], 32);
        a1[j] += __shfl_xor(a1[j], 16);
        a1[j] += __shfl_xor(a1[j], 32);
    }

    // self term (eps=0), loaded before the loop
    a0[0] += bf_lo(s0v.x); a0[1] += bf_hi(s0v.x);
    a0[2] += bf_lo(s0v.y); a0[3] += bf_hi(s0v.y);
    a0[4] += bf_lo(s0v.z); a0[5] += bf_hi(s0v.z);
    a0[6] += bf_lo(s0v.w); a0[7] += bf_hi(s0v.w);
    if (v1) {
        a1[0] += bf_lo(s1v.x); a1[1] += bf_hi(s1v.x);
        a1[2] += bf_lo(s1v.y); a1[3] += bf_hi(s1v.y);
        a1[4] += bf_lo(s1v.z); a1[5] += bf_hi(s1v.z);
        a1[6] += bf_lo(s1v.w); a1[7] += bf_hi(s1v.w);
    }

    if (grp == 0) {
        uint4 o;
        o.x = (unsigned)f2bf(a0[0]) | ((unsigned)f2bf(a0[1]) << 16);
        o.y = (unsigned)f2bf(a0[2]) | ((unsigned)f2bf(a0[3]) << 16);
        o.z = (unsigned)f2bf(a0[4]) | ((unsigned)f2bf(a0[5]) << 16);
        o.w = (unsigned)f2bf(a0[6]) | ((unsigned)f2bf(a0[7]) << 16);
        ((uint4*)y)[(size_t)n0 * 16 + sub] = o;
        if (v1) {
            uint4 p;
            p.x = (unsigned)f2bf(a1[0]) | ((unsigned)f2bf(a1[1]) << 16);
            p.y = (unsigned)f2bf(a1[2]) | ((unsigned)f2bf(a1[3]) << 16);
            p.z = (unsigned)f2bf(a1[4]) | ((unsigned)f2bf(a1[5]) << 16);
            p.w = (unsigned)f2bf(a1[6]) | ((unsigned)f2bf(a1[7]) << 16);
            ((uint4*)y)[(size_t)n1 * 16 + sub] = p;
        }
    }
}

// ---------------------------------------------------------------------------
// Fused layer GEMM: h = relu((relu((A@W1)*a1+b1_) @ W2) + b2_) + fused pool.
// Wt2 prefetched into registers BEFORE GEMM1 (latency hidden behind MFMAs).
// ---------------------------------------------------------------------------
__global__ __launch_bounds__(256) void layer_fused(const unsigned short* __restrict__ A,
                                                   const unsigned short* __restrict__ Wt1,
                                                   const unsigned short* __restrict__ Wt2,
                                                   const float* __restrict__ ea1,
                                                   const float* __restrict__ eb1,
                                                   const float* __restrict__ ea2,
                                                   const float* __restrict__ eb2,
                                                   const int* __restrict__ batch,
                                                   float* __restrict__ pooled, int loff,
                                                   unsigned short* __restrict__ outh, int n) {
    __shared__ unsigned short As[64][136];
    __shared__ unsigned short Ws[128][136];
    __shared__ int bgsh[64];
    int tid = threadIdx.x;
    int row0 = blockIdx.x * 64;
    int wave = tid >> 6, lane = tid & 63;
    int m0 = wave * 16;
    int lrow = lane & 15, lq = lane >> 4;

    #pragma unroll
    for (int i = 0; i < 4; ++i) {
        int idx = tid + i * 256;
        int r = idx >> 4, c = (idx & 15) * 8;
        ushort8 v = (ushort8)0;
        if (row0 + r < n) v = *(const ushort8*)&A[(size_t)(row0 + r) * D_FEAT + c];
        *(ushort8*)&As[r][c] = v;
    }
    #pragma unroll
    for (int i = 0; i < 8; ++i) {
        int idx = tid + i * 256;
        int r = idx >> 4, c = (idx & 15) * 8;
        *(ushort8*)&Ws[r][c] = *(const ushort8*)&Wt1[(size_t)r * D_FEAT + c];
    }
    if (tid < 64)
        bgsh[tid] = (row0 + tid < n) ? batch[row0 + tid] : -1;

    // prefetch Wt2 into registers — drains while GEMM1 runs
    ushort8 w2reg[8];
    #pragma unroll
    for (int i = 0; i < 8; ++i) {
        int idx = tid + i * 256;
        int r = idx >> 4, c = (idx & 15) * 8;
        w2reg[i] = *(const ushort8*)&Wt2[(size_t)r * D_FEAT + c];
    }
    __syncthreads();

    // ---- GEMM 1 ----
    f32x4 acc[8] = {};
    #pragma unroll
    for (int t = 0; t < 4; ++t) {
        bf16x8 a = *(const bf16x8*)&As[m0 + lrow][t * 32 + lq * 8];
        #pragma unroll
        for (int nt = 0; nt < 8; ++nt) {
            bf16x8 b = *(const bf16x8*)&Ws[nt * 16 + lrow][t * 32 + lq * 8];
            acc[nt] = __builtin_amdgcn_mfma_f32_16x16x32_bf16(a, b, acc[nt], 0, 0, 0);
        }
    }
    __syncthreads();

    // epilogue 1 -> z (bf16) into As; store prefetched Wt2 into Ws
    #pragma unroll
    for (int nt = 0; nt < 8; ++nt) {
        int col = nt * 16 + lrow;
        float al = ea1[col], be = eb1[col];
        #pragma unroll
        for (int r = 0; r < 4; ++r) {
            float v = fmaxf(fmaf(acc[nt][r], al, be), 0.f);
            As[m0 + lq * 4 + r][col] = f2bf(v);
        }
    }
    #pragma unroll
    for (int i = 0; i < 8; ++i) {
        int idx = tid + i * 256;
        int r = idx >> 4, c = (idx & 15) * 8;
        *(ushort8*)&Ws[r][c] = w2reg[i];
    }
    __syncthreads();

    // ---- GEMM 2 ----
    f32x4 acc2[8] = {};
    #pragma unroll
    for (int t = 0; t < 4; ++t) {
        bf16x8 a = *(const bf16x8*)&As[m0 + lrow][t * 32 + lq * 8];
        #pragma unroll
        for (int nt = 0; nt < 8; ++nt) {
            bf16x8 b = *(const bf16x8*)&Ws[nt * 16 + lrow][t * 32 + lq * 8];
            acc2[nt] = __builtin_amdgcn_mfma_f32_16x16x32_bf16(a, b, acc2[nt], 0, 0, 0);
        }
    }

    // epilogue 2 -> global h
    #pragma unroll
    for (int nt = 0; nt < 8; ++nt) {
        int col = nt * 16 + lrow;
        float al = ea2[col], be = eb2[col];
        #pragma unroll
        for (int r = 0; r < 4; ++r) {
            int grow = row0 + m0 + lq * 4 + r;
            if (grow < n) {
                float v = fmaxf(fmaf(acc2[nt][r], al, be), 0.f);
                outh[(size_t)grow * D_FEAT + col] = f2bf(v);
            }
        }
    }

    // ---- fused pooling ----
    __syncthreads();                       // all GEMM2 reads of Ws done
    float* Wsf = (float*)Ws;               // 64 x (stride 132) floats
    #pragma unroll
    for (int nt = 0; nt < 8; ++nt) {
        int col = nt * 16 + lrow;
        float al = ea2[col], be = eb2[col];
        #pragma unroll
        for (int r = 0; r < 4; ++r) {
            int lr = m0 + lq * 4 + r;
            float v = fmaxf(fmaf(acc2[nt][r], al, be), 0.f);
            Wsf[lr * 132 + col] = bf2f(f2bf(v));   // match bf16-rounded h
        }
    }
    __syncthreads();

    int c = tid & 127, half = tid >> 7;    // 2 halves x 32 rows each
    int rbeg = half * 32, rend = rbeg + 32;
    int cur = -1; float sum = 0.f;
    for (int r = rbeg; r < rend; ++r) {
        int g = bgsh[r];                   // uniform across the 128 col-threads
        if (g != cur) {
            if (cur >= 0) atomicAdd(&pooled[(size_t)cur * POOL_DIM + loff + c], sum);
            cur = g; sum = 0.f;
        }
        if (g >= 0) sum += Wsf[r * 132 + c];
    }
    if (cur >= 0) atomicAdd(&pooled[(size_t)cur * POOL_DIM + loff + c], sum);
}

// ---------------------------------------------------------------------------
// Fused MLP head: one block per graph. fc1 row -> LDS -> fc2 split-K.
// ---------------------------------------------------------------------------
__global__ __launch_bounds__(256) void head_kernel(const float* __restrict__ pooled,
                                                   const float* __restrict__ W1,
                                                   const float* __restrict__ b1v,
                                                   const float* __restrict__ W2,
                                                   const float* __restrict__ b2v,
                                                   float* __restrict__ out) {
    __shared__ float pr[POOL_DIM];
    __shared__ float f1[POOL_DIM];
    __shared__ float red[256];
    int g = blockIdx.x, tid = threadIdx.x;
    for (int i = tid; i < POOL_DIM; i += 256)
        pr[i] = pooled[(size_t)g * POOL_DIM + i];
    __syncthreads();
    for (int j = tid; j < POOL_DIM; j += 256) {
        float s = b1v[j];
        for (int k = 0; k < POOL_DIM; ++k)
            s = fmaf(pr[k], W1[(size_t)k * POOL_DIM + j], s);
        f1[j] = fmaxf(s, 0.f);
    }
    __syncthreads();
    float part = 0.f;
    int c = tid / 25;                       // 10 groups x 25 threads
    int r = tid % 25;
    if (tid < 250) {
        for (int k = r; k < POOL_DIM; k += 25)
            part = fmaf(f1[k], W2[(size_t)k * N_CLASSES + c], part);
    }
    red[tid] = part;
    __syncthreads();
    if (tid < N_CLASSES) {
        float s = b2v[tid];
        #pragma unroll
        for (int i = 0; i < 25; ++i) s += red[tid * 25 + i];
        out[(size_t)g * N_CLASSES + tid] = s;
    }
}

// ---------------------------------------------------------------------------
extern "C" void kernel_launch(void* const* d_in, const int* in_sizes, int n_in,
                              void* d_out, int out_size, void* d_ws, size_t ws_size,
                              hipStream_t stream) {
    const float* x      = (const float*)d_in[0];
    const int*   ei     = (const int*)  d_in[1];
    const int*   batch  = (const int*)  d_in[2];
    const float* W1     = (const float*)d_in[3];
    const float* b1     = (const float*)d_in[4];
    const float* gamma  = (const float*)d_in[5];
    const float* beta   = (const float*)d_in[6];
    const float* rm     = (const float*)d_in[7];
    const float* rv     = (const float*)d_in[8];
    const float* W2     = (const float*)d_in[9];
    const float* b2     = (const float*)d_in[10];
    const float* lin1W  = (const float*)d_in[11];
    const float* lin1b  = (const float*)d_in[12];
    const float* lin2W  = (const float*)d_in[13];
    const float* lin2b  = (const float*)d_in[14];
    float* out = (float*)d_out;

    const int N = in_sizes[0] / D_FEAT;   // 50000
    const int E = in_sizes[1] / 2;        // 800000

    char* ws = (char*)d_ws;
    auto carve = [&](size_t bytes) {
        char* p = ws;
        ws += (bytes + 255) & ~(size_t)255;
        return p;
    };
    int*   cursor    = (int*)  carve((size_t)N * 4);
    int*   cnts      = (int*)  carve((size_t)NBINS * 256 * 4);
    int*   bucket    = (int*)  carve((size_t)N * CAP * 4);
    int2*  pairs     = (int2*) carve((size_t)NBINS * 256 * SLABCAP * 8);
    float* ea        = (float*)carve((size_t)2 * N_LAYERS * D_FEAT * 4);
    float* eb        = (float*)carve((size_t)2 * N_LAYERS * D_FEAT * 4);
    unsigned short* Wt   = (unsigned short*)carve((size_t)2 * N_LAYERS * D_FEAT * D_FEAT * 2);
    unsigned short* xb   = (unsigned short*)carve((size_t)N * D_FEAT * 2);
    unsigned short* ybuf = (unsigned short*)carve((size_t)N * D_FEAT * 2);
    unsigned short* hbuf = (unsigned short*)carve((size_t)N * D_FEAT * 2);
    float* pooled    = (float*)carve((size_t)N_GRAPHS * POOL_DIM * 4);

    // merged setup grid layout
    const int n4 = N * D_FEAT / 4;
    const int B0 = (n4 + 255) / 256;                            // cvt_x
    const int B1 = B0 + (2 * N_LAYERS * D_FEAT * D_FEAT) / 256; // cvt_w (exact)
    const int B2 = B1 + 2;                                      // prep
    const int B3 = B2 + (N + 255) / 256;                        // cursor zero
    const int B4 = B3 + (N_GRAPHS * POOL_DIM + 255) / 256;      // pooled zero
    const int B5 = B4 + 256;                                    // bin

    setup_kernel<<<B5, 256, 0, stream>>>(x, xb, W1, W2, Wt, b1, gamma, beta,
                                         rm, rv, b2, ea, eb, cursor, pooled,
                                         ei, pairs, cnts, E,
                                         N, n4, B0, B1, B2, B3, B4);
    fill_v3<<<8 * 64, 256, 0, stream>>>(pairs, cnts, cursor, bucket);

    const unsigned short* hprev = xb;
    for (int l = 0; l < N_LAYERS; ++l) {
        agg_kernel<<<(N + 7) / 8, 256, 0, stream>>>(hprev, cursor, bucket, ybuf, N);
        layer_fused<<<(N + 63) / 64, 256, 0, stream>>>(ybuf,
                      Wt + (size_t)(2 * l) * D_FEAT * D_FEAT,
                      Wt + (size_t)(2 * l + 1) * D_FEAT * D_FEAT,
                      ea + (size_t)(2 * l) * D_FEAT,
                      eb + (size_t)(2 * l) * D_FEAT,
                      ea + (size_t)(2 * l + 1) * D_FEAT,
                      eb + (size_t)(2 * l + 1) * D_FEAT,
                      batch, pooled, l * D_FEAT, hbuf, N);
        hprev = hbuf;
    }
    head_kernel<<<N_GRAPHS, 256, 0, stream>>>(pooled, lin1W, lin1b, lin2W, lin2b, out);
}